// Round 13
// baseline (103.033 us; speedup 1.0000x reference)
//
#include <hip/hip_runtime.h>
#include <hip/hip_bf16.h>
#include <cstdint>

#define HDIM 2048
#define INDIM 4096
#define CDIM 4096
#define KDIM 2048   // GEMM K = hidden size

typedef __attribute__((ext_vector_type(4))) int int4v;

__device__ __forceinline__ void gload16(const void* g, void* l) {
  __builtin_amdgcn_global_load_lds(
      (const __attribute__((address_space(1))) void*)g,
      (__attribute__((address_space(3))) void*)l, 16, 0, 0);
}

#define LOADPIN() asm volatile("s_waitcnt vmcnt(0)" ::: "memory")
#define WAITCNT4() asm volatile("s_waitcnt vmcnt(4)" ::: "memory")
// raw workgroup barrier, order-pinned (rule #18)
#define WGBAR()                                   \
  do {                                            \
    __builtin_amdgcn_sched_barrier(0);            \
    __builtin_amdgcn_s_barrier();                 \
    __builtin_amdgcn_sched_barrier(0);            \
  } while (0)

__device__ __forceinline__ float dot4(float4 a, float4 b) {
  return a.x * b.x + a.y * b.y + a.z * b.z + a.w * b.w;
}

// ---------------- Kernel 1: i8 row-quant + xa2 GEMV (92 MB, full occupancy) ---
__global__ __launch_bounds__(256) void k_quant_xa2(
    const float* __restrict__ c_input, const float* __restrict__ aW_hh,
    int8_t* __restrict__ a8, int8_t* __restrict__ b8,
    float* __restrict__ dAs, float* __restrict__ dBs,
    const float* __restrict__ x,
    const float* __restrict__ aW_ih, const float* __restrict__ ab_ih,
    const float* __restrict__ ab_hh,
    float* __restrict__ xa2, float* __restrict__ accz) {
  const int t = threadIdx.x;
  const int wid = t >> 6, lane = t & 63;

  if (blockIdx.x < 1536) {
    if (blockIdx.x == 0) {  // zero acc_se/acc_sce (4096 floats) every launch
#pragma unroll
      for (int i = 0; i < 16; ++i) accz[i * 256 + t] = 0.f;
    }
    const int row = blockIdx.x * 4 + wid;
    const float* src; int8_t* dst; float* dsc; int r;
    if (row < CDIM) { src = c_input; dst = a8; dsc = dAs; r = row; }
    else            { src = aW_hh;  dst = b8; dsc = dBs; r = row - CDIM; }
    const float4* s4 = (const float4*)(src + (size_t)r * KDIM);
    float4 v[8];
#pragma unroll
    for (int it = 0; it < 8; ++it) v[it] = s4[it * 64 + lane];
    LOADPIN();
    float am = 0.f;
#pragma unroll
    for (int it = 0; it < 8; ++it)
      am = fmaxf(am, fmaxf(fmaxf(fabsf(v[it].x), fabsf(v[it].y)),
                           fmaxf(fabsf(v[it].z), fabsf(v[it].w))));
#pragma unroll
    for (int off = 32; off > 0; off >>= 1) am = fmaxf(am, __shfl_xor(am, off));
    am = fmaxf(am, 1e-20f);
    const float inv = 127.0f / am;
    uint32_t* qd = (uint32_t*)(dst + (size_t)r * KDIM);
#pragma unroll
    for (int it = 0; it < 8; ++it) {
      uint32_t p = (uint32_t)(__float2int_rn(v[it].x * inv) & 0xFF)
                 | ((uint32_t)(__float2int_rn(v[it].y * inv) & 0xFF) << 8)
                 | ((uint32_t)(__float2int_rn(v[it].z * inv) & 0xFF) << 16)
                 | ((uint32_t)(__float2int_rn(v[it].w * inv) & 0xFF) << 24);
      qd[it * 64 + lane] = p;
    }
    if (lane == 0) dsc[r] = am * (1.0f / 127.0f);
    return;
  }

  // ---- xa2 GEMV: one wave per h ----
  const int h = (blockIdx.x - 1536) * 4 + wid;
  const float4* x4 = (const float4*)x;
  const float4* wr4 = (const float4*)(aW_ih + (size_t)h * INDIM);
  float sum = 0.f;
#pragma unroll
  for (int g = 0; g < 2; ++g) {
    float4 w[8];
#pragma unroll
    for (int it = 0; it < 8; ++it) w[it] = wr4[(g * 8 + it) * 64 + lane];
    LOADPIN();
#pragma unroll
    for (int it = 0; it < 8; ++it)
      sum += dot4(w[it], x4[(g * 8 + it) * 64 + lane]);
  }
#pragma unroll
  for (int off = 32; off > 0; off >>= 1) sum += __shfl_down(sum, off);
  if (lane == 0) xa2[h] = sum + ab_ih[h] + ab_hh[h];
}

// ---------------- Kernel 2: lockstep fat kernel (r11 fixed) -------------------
// 512 blocks x 512 threads, 2 blocks/CU -> every CU: 8 GEMM + 8 GEMV waves.
// GEMM waves 0-3: 128x128 tile, 3-buffer LDS ring, DISTANCE-2 prefetch with
//   counted vmcnt(4) (4 gload_lds per thread per STAGE) — never waits on loads
//   issued this interval, so streamer VMEM congestion can't stretch the loop.
// GEMV waves 4-7: one h per wave; 9 batches x 8 loads (8 KB/wave in flight),
//   batch b issued at interval 3b, consumed at 3b+3 — the consume-time
//   vmcnt(0) is a no-op (~2 us after issue). This is the r11 fix: r11 issued
//   only 2 loads/interval then slept at the barrier (the real throttle).
// BOTH paths: exactly 33 s_barriers (1 prologue + 32 loop).
// LDS swizzle p(r)=((r>>1)&3): 2-way residual = free (r6 fix, r7-verified 0).
__global__ __launch_bounds__(512, 4) void k_fused(
    const int8_t* __restrict__ A, const int8_t* __restrict__ B,
    const float* __restrict__ dAs, const float* __restrict__ dBs,
    const float* __restrict__ xa2,
    float* __restrict__ acc_se, float* __restrict__ acc_sce,
    const float* __restrict__ x, const float* __restrict__ h0,
    const float* __restrict__ W_ih, const float* __restrict__ W_hh,
    const float* __restrict__ b_ih, const float* __restrict__ b_hh,
    float* __restrict__ i_sig, float* __restrict__ o_sig,
    float* __restrict__ g_tanh) {
  __shared__ uint8_t As[3][8192];  // 3-buffer ring, 48 KB total
  __shared__ uint8_t Bs[3][8192];
  const int t = threadIdx.x;
  const int lane = t & 63, wid = t >> 6;
  const int bid = blockIdx.x;

  if (wid < 4) {
    // ================= GEMM waves (threads 0..255) =================
    const int wr = wid >> 1, wc = wid & 1;
    const int l15 = lane & 15, l4 = lane >> 4;
    const int bn = (bid & 7) * 2 + ((bid >> 3) & 1);  // XCD-grouped B panels
    const int bm = bid >> 4;
    const int m0 = bm * 128, n0 = bn * 128;

    int4v acc[4][4] = {};

    const int trow = t >> 2;
    const int tcol = (((t & 3) ^ ((trow >> 1) & 3)) * 16);  // pre-swizzled src
    const int8_t* Arow = A + (size_t)(m0 + trow) * KDIM + tcol;
    const int8_t* Brow = B + (size_t)(n0 + trow) * KDIM + tcol;

#define STAGE(buf, kt)                                                          \
    do {                                                                        \
      _Pragma("unroll")                                                         \
      for (int qq = 0; qq < 2; ++qq) {                                          \
        gload16(Arow + (size_t)qq * 64 * KDIM + (size_t)(kt) * 64,              \
                As[buf] + qq * 4096 + t * 16);                                  \
        gload16(Brow + (size_t)qq * 64 * KDIM + (size_t)(kt) * 64,              \
                Bs[buf] + qq * 4096 + t * 16);                                  \
      }                                                                         \
    } while (0)

    STAGE(0, 0);
    STAGE(1, 1);     // 8 loads/thread outstanding
    WAITCNT4();      // batch for buf0 landed
    WGBAR();         // barrier #0

    for (int ti = 0; ti < 32; ++ti) {
      const int cur = ti % 3;
      int4v af[4], bfr[4];
#pragma unroll
      for (int m = 0; m < 4; ++m) {
        const int r = wr * 64 + m * 16 + l15;
        af[m] = *(const int4v*)(As[cur] + r * 64 + ((l4 ^ ((r >> 1) & 3)) * 16));
      }
#pragma unroll
      for (int n = 0; n < 4; ++n) {
        const int r = wc * 64 + n * 16 + l15;
        bfr[n] = *(const int4v*)(Bs[cur] + r * 64 + ((l4 ^ ((r >> 1) & 3)) * 16));
      }
      if (ti < 30) STAGE((ti + 2) % 3, ti + 2);  // distance-2 prefetch
#pragma unroll
      for (int m = 0; m < 4; ++m)
#pragma unroll
        for (int n = 0; n < 4; ++n)
          acc[m][n] = __builtin_amdgcn_mfma_i32_16x16x64_i8(af[m], bfr[n], acc[m][n], 0, 0, 0);
      if (ti < 30) { WAITCNT4(); }   // batch(ti-1) done -> buf[(ti+1)%3] ready
      else         { LOADPIN();  }   // drain the final batch
      WGBAR();                        // barriers #1..#32
    }
#undef STAGE

    // epilogue: D layout col = lane&15, row = (lane>>4)*4 + reg [m89-verified]
    // merge term dequants a8 (L3-hot; r9/r12-validated absmax 4.9e-4)
#pragma unroll
    for (int n = 0; n < 4; ++n) {
      const int hcol = n0 + wc * 64 + n * 16 + l15;
      const float xa = xa2[hcol];
      const float db = dBs[hcol];
      float se = 0.f, sce = 0.f;
#pragma unroll
      for (int m = 0; m < 4; ++m) {
        const int jbase = m0 + wr * 64 + m * 16 + l4 * 4;
#pragma unroll
        for (int rr = 0; rr < 4; ++rr) {
          const float da = dAs[jbase + rr];
          float z = (float)acc[m][n][rr] * (da * db) + xa;
          float s = 1.f / (1.f + __expf(-z));
          float e = __expf(s);
          se += e;
          sce += (float)A[(size_t)(jbase + rr) * KDIM + hcol] * (da * e);
        }
      }
      se += __shfl_xor(se, 16); se += __shfl_xor(se, 32);
      sce += __shfl_xor(sce, 16); sce += __shfl_xor(sce, 32);
      if (l4 == 0) {
        atomicAdd(&acc_se[hcol], se);
        atomicAdd(&acc_sce[hcol], sce);
      }
    }
    return;
  }

  // ================= GEMV waves (threads 256..511) =================
  // one h per wave; batches: b=0..5 -> W_ih rows {i,o,g} x halves, b=6..8 ->
  // W_hh rows {i,o,g}. Issue batch b at interval 3b, consume at 3b+3.
  const int h = bid * 4 + (wid - 4);  // [0, 2048)
  const float4* WIi = (const float4*)(W_ih + (size_t)h * INDIM);
  const float4* WIo = (const float4*)(W_ih + (size_t)(2 * HDIM + h) * INDIM);
  const float4* WIg = (const float4*)(W_ih + (size_t)(3 * HDIM + h) * INDIM);
  const float4* WHi = (const float4*)(W_hh + (size_t)h * HDIM);
  const float4* WHo = (const float4*)(W_hh + (size_t)(2 * HDIM + h) * HDIM);
  const float4* WHg = (const float4*)(W_hh + (size_t)(3 * HDIM + h) * HDIM);
  const float4* x4 = (const float4*)x;
  const float4* h4 = (const float4*)h0;
  float sI = 0.f, sO = 0.f, sG = 0.f;
  float4 w[8];

  // bb is always a compile-time literal -> all selects fold (rule #20 safe)
#define BPTR(bb) ((bb) < 6 ? ((((bb) >> 1) == 0) ? WIi : (((bb) >> 1) == 1) ? WIo : WIg) + ((bb) & 1) * 512 \
                           : (((bb) == 6) ? WHi : ((bb) == 7) ? WHo : WHg))
#define ISSUE(bb)                                                   \
  do {                                                              \
    const float4* _s = BPTR(bb);                                    \
    _Pragma("unroll")                                               \
    for (int it = 0; it < 8; ++it) w[it] = _s[it * 64 + lane];      \
  } while (0)
#define CONSUME(bb)                                                 \
  do {                                                              \
    LOADPIN(); /* batch landed ~2 intervals ago: no-op wait */      \
    _Pragma("unroll")                                               \
    for (int it = 0; it < 8; ++it) {                                \
      float4 _xv = ((bb) < 6) ? x4[((bb) & 1) * 512 + it * 64 + lane] \
                              : h4[it * 64 + lane];                 \
      float _d = dot4(w[it], _xv);                                  \
      if (((bb) < 6 && ((bb) >> 1) == 0) || (bb) == 6) sI += _d;    \
      else if (((bb) < 6 && ((bb) >> 1) == 1) || (bb) == 7) sO += _d; \
      else sG += _d;                                                \
    }                                                               \
  } while (0)

  ISSUE(0);
  WGBAR();  // barrier #0
#pragma unroll
  for (int m = 1; m <= 32; ++m) {
    if (m % 3 == 0) {
      const int b = m / 3 - 1;  // constant under full unroll
      switch (b) {
        case 0: CONSUME(0); ISSUE(1); break;
        case 1: CONSUME(1); ISSUE(2); break;
        case 2: CONSUME(2); ISSUE(3); break;
        case 3: CONSUME(3); ISSUE(4); break;
        case 4: CONSUME(4); ISSUE(5); break;
        case 5: CONSUME(5); ISSUE(6); break;
        case 6: CONSUME(6); ISSUE(7); break;
        case 7: CONSUME(7); ISSUE(8); break;
        case 8: CONSUME(8); break;
        default: break;  // b == 9 (m == 30): idle
      }
    }
    WGBAR();  // barriers #1..#32
  }
#undef BPTR
#undef ISSUE
#undef CONSUME

#pragma unroll
  for (int off = 32; off > 0; off >>= 1) {
    sI += __shfl_down(sI, off);
    sO += __shfl_down(sO, off);
    sG += __shfl_down(sG, off);
  }
  if (lane == 0) {
    float zI = sI + b_ih[h] + b_hh[h];
    float zO = sO + b_ih[2 * HDIM + h] + b_hh[2 * HDIM + h];
    float zG = sG + b_ih[3 * HDIM + h] + b_hh[3 * HDIM + h];
    i_sig[h] = 1.f / (1.f + expf(-zI));
    o_sig[h] = 1.f / (1.f + expf(-zO));
    g_tanh[h] = tanhf(zG);
  }
}

// ---------------- Kernel 3: finalize ------------------------------------------
__global__ __launch_bounds__(256) void k_final(
    const float* __restrict__ i_sig, const float* __restrict__ o_sig,
    const float* __restrict__ g_tanh, const float* __restrict__ acc_se,
    const float* __restrict__ acc_sce, float* __restrict__ out) {
  int h = blockIdx.x * 256 + threadIdx.x;
  if (h >= HDIM) return;
  float wi = expf(i_sig[h]);
  float tot = acc_se[h] + wi;
  float c1 = (acc_sce[h] + g_tanh[h] * wi) / tot;
  float h1 = o_sig[h] * tanhf(c1);
  out[h] = h1;
  out[HDIM + h] = c1;
}

extern "C" void kernel_launch(void* const* d_in, const int* in_sizes, int n_in,
                              void* d_out, int out_size, void* d_ws, size_t ws_size,
                              hipStream_t stream) {
  const float* x     = (const float*)d_in[0];
  const float* c_inp = (const float*)d_in[1];
  const float* h0    = (const float*)d_in[2];
  // d_in[3] = c0: unused by the reference output
  const float* W_ih  = (const float*)d_in[4];
  const float* b_ih  = (const float*)d_in[5];
  const float* W_hh  = (const float*)d_in[6];
  const float* b_hh  = (const float*)d_in[7];
  const float* aW_ih = (const float*)d_in[8];
  const float* ab_ih = (const float*)d_in[9];
  const float* aW_hh = (const float*)d_in[10];
  const float* ab_hh = (const float*)d_in[11];
  float* out = (float*)d_out;

  char* ws = (char*)d_ws;
  int8_t* a8 = (int8_t*)ws;                          // 8 MB i8 c_input
  int8_t* b8 = a8 + (size_t)CDIM * KDIM;             // 4 MB i8 aW_hh
  float* dAs = (float*)(b8 + (size_t)HDIM * KDIM);   // 16 KB row scales A
  float* dBs = dAs + CDIM;                           // 8 KB row scales B
  float* fb  = dBs + HDIM;
  float* xa2     = fb;
  float* acc_se  = fb + HDIM;      // acc_se/acc_sce contiguous: zeroed together
  float* acc_sce = fb + 2 * HDIM;
  float* i_sig   = fb + 3 * HDIM;
  float* o_sig   = fb + 4 * HDIM;
  float* g_tanh  = fb + 5 * HDIM;

  // k1: quant (6144 rows) + xa2 (92 MB, full occupancy)
  k_quant_xa2<<<2048, 256, 0, stream>>>(
      c_inp, aW_hh, a8, b8, dAs, dBs, x, aW_ih, ab_ih, ab_hh, xa2, acc_se);
  // k2: lockstep GEMM || 144 MB gate streaming
  k_fused<<<512, 512, 0, stream>>>(
      a8, b8, dAs, dBs, xa2, acc_se, acc_sce,
      x, h0, W_ih, W_hh, b_ih, b_hh, i_sig, o_sig, g_tanh);
  k_final<<<(HDIM + 255) / 256, 256, 0, stream>>>(i_sig, o_sig, g_tanh,
                                                  acc_se, acc_sce, out);
}